// Round 9
// baseline (795.067 us; speedup 1.0000x reference)
//
#include <hip/hip_runtime.h>
#include <hip/hip_bf16.h>

// GINE 3-conv GNN. Dst-grouped slot layout via zero-global-atomic two-level
// counting sort (round-8 structure). This round: non-temporal loads/stores on
// all single-use streaming data (srec/ebuf/ea_s/brec16/ei/ea) so the small
// reused gather tables (xnbf/Pa/Pc, 9.6MB) stay L2-resident instead of being
// evicted by the 100MB+ streams (kagg16_s showed 205MB of xnbf line refetch).
// N=100000, E=3200000, H=16. fp32 in/out; edge_index int32 rows [src | dst].

#define NN 100000
#define NE 3200000
#define NBKT 782          // ceil(NN/128)
#define BSHIFT 7
#define LMASK 127
#define NBLK1 1024        // pass-1 blocks
#define EPB1 3125         // NE / NBLK1 (exact)

__device__ __forceinline__ float bf2f(unsigned int h) {
    unsigned int u = h << 16;
    float f; __builtin_memcpy(&f, &u, 4); return f;
}
__device__ __forceinline__ unsigned short f2bf(float f) {
    unsigned int u; __builtin_memcpy(&u, &f, 4);
    u += 0x7fffu + ((u >> 16) & 1u);          // RNE
    return (unsigned short)(u >> 16);
}

// ---- non-temporal helpers (streaming, bypass L2 residency) ----
__device__ __forceinline__ unsigned long long ldnt_u64(const void* p) {
    return __builtin_nontemporal_load(reinterpret_cast<const unsigned long long*>(p));
}
__device__ __forceinline__ uint2 ldnt_u2(const void* p) {
    unsigned long long v = ldnt_u64(p);
    return make_uint2((unsigned int)v, (unsigned int)(v >> 32));
}
__device__ __forceinline__ void stnt_u64(void* p, unsigned long long v) {
    __builtin_nontemporal_store(v, reinterpret_cast<unsigned long long*>(p));
}
__device__ __forceinline__ int ldnt_i32(const void* p) {
    return __builtin_nontemporal_load(reinterpret_cast<const int*>(p));
}
__device__ __forceinline__ float ldnt_f32(const void* p) {
    return __builtin_nontemporal_load(reinterpret_cast<const float*>(p));
}

// cached 32B row load/store (bf16 x16)
__device__ __forceinline__ void ldbf16x16(const unsigned short* p, float* r) {
    const uint4* q = reinterpret_cast<const uint4*>(p);
    uint4 a = q[0], b = q[1];
    unsigned int w[8] = {a.x, a.y, a.z, a.w, b.x, b.y, b.z, b.w};
    #pragma unroll
    for (int k = 0; k < 8; ++k) {
        r[2*k]   = bf2f(w[k] & 0xffffu);
        r[2*k+1] = bf2f(w[k] >> 16);
    }
}
// non-temporal 32B row load/store (bf16 x16), via 4x 8B
__device__ __forceinline__ void ldbf16x16_nt(const unsigned short* p, float* r) {
    unsigned long long v[4];
    #pragma unroll
    for (int k = 0; k < 4; ++k) v[k] = ldnt_u64(p + 4*k);
    #pragma unroll
    for (int k = 0; k < 4; ++k) {
        r[4*k+0] = bf2f((unsigned int)(v[k]       ) & 0xffffu);
        r[4*k+1] = bf2f((unsigned int)(v[k] >> 16 ) & 0xffffu);
        r[4*k+2] = bf2f((unsigned int)(v[k] >> 32 ) & 0xffffu);
        r[4*k+3] = bf2f((unsigned int)(v[k] >> 48 ));
    }
}
__device__ __forceinline__ void stbf16x16(unsigned short* p, const float* r) {
    unsigned int w[8];
    #pragma unroll
    for (int k = 0; k < 8; ++k)
        w[k] = (unsigned int)f2bf(r[2*k]) | ((unsigned int)f2bf(r[2*k+1]) << 16);
    uint4* q = reinterpret_cast<uint4*>(p);
    q[0] = make_uint4(w[0], w[1], w[2], w[3]);
    q[1] = make_uint4(w[4], w[5], w[6], w[7]);
}
__device__ __forceinline__ void stbf16x16_nt(unsigned short* p, const float* r) {
    #pragma unroll
    for (int k = 0; k < 4; ++k) {
        unsigned long long v =
              (unsigned long long)f2bf(r[4*k+0])
            | ((unsigned long long)f2bf(r[4*k+1]) << 16)
            | ((unsigned long long)f2bf(r[4*k+2]) << 32)
            | ((unsigned long long)f2bf(r[4*k+3]) << 48);
        stnt_u64(p + 4*k, v);
    }
}

// ---------------- build: two-level counting sort (no global atomics) ----------------

__global__ void khist1(const int* __restrict__ ei, int* __restrict__ hist) {
    __shared__ int h[NBKT];
    int blk = blockIdx.x, tid = threadIdx.x;
    for (int b = tid; b < NBKT; b += 256) h[b] = 0;
    __syncthreads();
    int e0 = blk * EPB1;
    for (int e = e0 + tid; e < e0 + EPB1; e += 256)
        atomicAdd(&h[ldnt_i32(&ei[NE + e]) >> BSHIFT], 1);   // LDS atomic
    __syncthreads();
    for (int b = tid; b < NBKT; b += 256) hist[b * NBLK1 + blk] = h[b];
}

__global__ void kscan_a(int* __restrict__ hist, int* __restrict__ binsum) {
    __shared__ int s[NBLK1];
    int b = blockIdx.x, t = threadIdx.x;
    int v = hist[b * NBLK1 + t];
    s[t] = v; __syncthreads();
    for (int off = 1; off < NBLK1; off <<= 1) {
        int u = (t >= off) ? s[t - off] : 0;
        __syncthreads();
        s[t] += u;
        __syncthreads();
    }
    hist[b * NBLK1 + t] = s[t] - v;                 // exclusive within bin
    if (t == NBLK1 - 1) binsum[b] = s[t];
}

__global__ void kscan_b(const int* __restrict__ binsum, int* __restrict__ binbase,
                        int* __restrict__ start) {
    __shared__ int s[1024];
    int t = threadIdx.x;
    int v = (t < NBKT) ? binsum[t] : 0;
    s[t] = v; __syncthreads();
    for (int off = 1; off < 1024; off <<= 1) {
        int u = (t >= off) ? s[t - off] : 0;
        __syncthreads();
        s[t] += u;
        __syncthreads();
    }
    if (t < NBKT) binbase[t] = s[t] - v;
    if (t == NBKT - 1) binbase[NBKT] = s[t];        // == NE
    if (t == 0) start[NN] = NE;
}

__global__ void kscatter1(const int* __restrict__ ei, const float* __restrict__ ea,
                          const int* __restrict__ hist, const int* __restrict__ binbase,
                          uint4* __restrict__ brec16) {
    __shared__ int cur[NBKT];
    int blk = blockIdx.x, tid = threadIdx.x;
    for (int b = tid; b < NBKT; b += 256)
        cur[b] = binbase[b] + hist[b * NBLK1 + blk];
    __syncthreads();
    int e0 = blk * EPB1;
    for (int e = e0 + tid; e < e0 + EPB1; e += 256) {
        int s = ldnt_i32(&ei[e]), d = ldnt_i32(&ei[NE + e]);
        float f0 = ldnt_f32(&ea[(size_t)3*e]);
        float f1 = ldnt_f32(&ea[(size_t)3*e+1]);
        float f2 = ldnt_f32(&ea[(size_t)3*e+2]);
        int pos = atomicAdd(&cur[d >> BSHIFT], 1);  // LDS atomic
        unsigned long long u = (unsigned long long)(unsigned int)s
                             | ((unsigned long long)(unsigned int)d << 17)
                             | ((unsigned long long)(unsigned int)e << 34);
        uint4 r;
        r.x = (unsigned int)u;
        r.y = (unsigned int)(u >> 32);
        r.z = (unsigned int)f2bf(f0) | ((unsigned int)f2bf(f1) << 16);
        r.w = (unsigned int)f2bf(f2);
        brec16[pos] = r;                            // scattered: keep cached (L2 merges)
    }
}

__global__ void kbucket(const uint4* __restrict__ brec16, const int* __restrict__ binbase,
                        unsigned long long* __restrict__ srec, unsigned int* __restrict__ ea_s,
                        int* __restrict__ start) {
    __shared__ int cnt[128];
    __shared__ int off[128];
    __shared__ int cur[128];
    int bkt = blockIdx.x, t = threadIdx.x;
    int base = binbase[bkt], end = binbase[bkt + 1];
    if (t < 128) cnt[t] = 0;
    __syncthreads();
    for (int j = base + t; j < end; j += 256) {
        unsigned long long lo = ldnt_u64(&brec16[j]);      // first 8B of record
        int dl = (int)((lo >> 17) & 0x1FFFFu) & LMASK;
        atomicAdd(&cnt[dl], 1);
    }
    __syncthreads();
    if (t < 128) { off[t] = cnt[t]; }
    __syncthreads();
    for (int o = 1; o < 128; o <<= 1) {
        int u = (t < 128 && t >= o) ? off[t - o] : 0;
        __syncthreads();
        if (t < 128) off[t] += u;
        __syncthreads();
    }
    if (t < 128) {
        int excl = off[t] - cnt[t];
        int node = bkt * 128 + t;
        if (node < NN) start[node] = base + excl;
        cur[t] = base + excl;
    }
    __syncthreads();
    for (int j = base + t; j < end; j += 256) {
        const unsigned long long* rp = reinterpret_cast<const unsigned long long*>(&brec16[j]);
        unsigned long long lo = ldnt_u64(rp);
        unsigned long long hi = ldnt_u64(rp + 1);
        int dl = (int)((lo >> 17) & 0x1FFFFu) & LMASK;
        int p = atomicAdd(&cur[dl], 1);
        srec[p] = lo;                                // in-bucket scatter: cached
        *reinterpret_cast<unsigned long long*>(&ea_s[(size_t)2*p]) = hi;
    }
}

// ---------------- aggregations (CSR streaming) ----------------

// conv1: agg3[n] = sum relu(x[src]+ea); 4 threads/node interleaved + shfl reduce
__global__ void kagg3_s(const int* __restrict__ start, const unsigned long long* __restrict__ srec,
                        const unsigned int* __restrict__ ea_s,
                        const float* __restrict__ x, float* __restrict__ agg) {
    int t = blockIdx.x * blockDim.x + threadIdx.x;
    int n = t >> 2, q = t & 3;
    if (n >= NN) return;
    int j0 = start[n], j1 = start[n + 1];
    float a0 = 0.f, a1 = 0.f, a2 = 0.f;
    for (int j = j0 + q; j < j1; j += 4) {
        unsigned long long sr = ldnt_u64(&srec[j]);
        int s = (int)(sr & 0x1FFFFu);
        uint2 w = ldnt_u2(&ea_s[(size_t)2*j]);
        a0 += fmaxf(x[3*s  ] + bf2f(w.x & 0xffffu), 0.f);
        a1 += fmaxf(x[3*s+1] + bf2f(w.x >> 16),     0.f);
        a2 += fmaxf(x[3*s+2] + bf2f(w.y & 0xffffu), 0.f);
    }
    a0 += __shfl_xor(a0, 1); a0 += __shfl_xor(a0, 2);
    a1 += __shfl_xor(a1, 1); a1 += __shfl_xor(a1, 2);
    a2 += __shfl_xor(a2, 1); a2 += __shfl_xor(a2, 2);
    if (q == 0) {
        float* p = agg + (size_t)n*16;
        p[0] = a0; p[1] = a1; p[2] = a2;
    }
}

// conv2/3: 4 threads/node, 4 dims each; streams srec/ebuf NT, xnbf cached.
__global__ void kagg16_s(const int* __restrict__ start, const unsigned long long* __restrict__ srec,
                         const unsigned short* __restrict__ ebuf,
                         const unsigned short* __restrict__ xnbf, float* __restrict__ agg) {
    int tg = blockIdx.x * blockDim.x + threadIdx.x;
    int n = tg >> 2, q = tg & 3;
    if (n >= NN) return;
    int j0 = start[n], j1 = start[n + 1];
    float a0 = 0.f, a1 = 0.f, a2 = 0.f, a3 = 0.f;
    for (int j = j0; j < j1; ++j) {
        unsigned long long sr = ldnt_u64(&srec[j]);
        int s = (int)(sr & 0x1FFFFu);
        uint2 w  = ldnt_u2(ebuf + (size_t)j*16 + q*4);
        uint2 xw = *reinterpret_cast<const uint2*>(xnbf + (size_t)s*16 + q*4);  // cached
        a0 += fmaxf(bf2f(xw.x & 0xffffu) + bf2f(w.x & 0xffffu), 0.f);
        a1 += fmaxf(bf2f(xw.x >> 16)     + bf2f(w.x >> 16),     0.f);
        a2 += fmaxf(bf2f(xw.y & 0xffffu) + bf2f(w.y & 0xffffu), 0.f);
        a3 += fmaxf(bf2f(xw.y >> 16)     + bf2f(w.y >> 16),     0.f);
    }
    *reinterpret_cast<float4*>(agg + (size_t)n*16 + q*4) = make_float4(a0, a1, a2, a3);
}

// ---------------- node-side kernels ----------------

__global__ void prep1(const float* __restrict__ x, const float* __restrict__ ew1,
                      unsigned short* __restrict__ Pa, unsigned short* __restrict__ Pc) {
    int n = blockIdx.x * blockDim.x + threadIdx.x;
    if (n >= NN) return;
    float x0 = x[3*n], x1 = x[3*n+1], x2 = x[3*n+2];
    float pa[16], pc[16];
    #pragma unroll
    for (int j = 0; j < 16; ++j) {
        pa[j] = x0*ew1[0*16+j] + x1*ew1[1*16+j] + x2*ew1[2*16+j];
        pc[j] = x0*ew1[6*16+j] + x1*ew1[7*16+j] + x2*ew1[8*16+j];
    }
    stbf16x16(Pa + (size_t)n*16, pa);
    stbf16x16(Pc + (size_t)n*16, pc);
}

__global__ void conv1_node(const float* __restrict__ agg, const float* __restrict__ x,
                           const float* __restrict__ nw1, const float* __restrict__ nb1,
                           const float* __restrict__ nw2, const float* __restrict__ nb2,
                           const float* __restrict__ next_ew1,
                           unsigned short* __restrict__ Pa, unsigned short* __restrict__ Pc,
                           unsigned short* __restrict__ xnbf) {
    int n = blockIdx.x * blockDim.x + threadIdx.x;
    if (n >= NN) return;
    float o0 = agg[(size_t)n*16+0] + x[3*n];
    float o1 = agg[(size_t)n*16+1] + x[3*n+1];
    float o2 = agg[(size_t)n*16+2] + x[3*n+2];
    float h[16];
    #pragma unroll
    for (int j = 0; j < 16; ++j)
        h[j] = fmaxf(nb1[j] + o0*nw1[0*16+j] + o1*nw1[1*16+j] + o2*nw1[2*16+j], 0.f);
    float xn[16];
    #pragma unroll
    for (int j = 0; j < 16; ++j) {
        float a = nb2[j];
        #pragma unroll
        for (int i = 0; i < 16; ++i) a = fmaf(h[i], nw2[i*16+j], a);
        xn[j] = fmaxf(a, 0.f);
    }
    float pa[16], pc[16];
    #pragma unroll
    for (int j = 0; j < 16; ++j) {
        float sa = 0.f, sc = 0.f;
        #pragma unroll
        for (int i = 0; i < 16; ++i) {
            sa = fmaf(xn[i], next_ew1[i*16+j], sa);
            sc = fmaf(xn[i], next_ew1[(32+i)*16+j], sc);
        }
        pa[j] = sa; pc[j] = sc;
    }
    stbf16x16(xnbf + (size_t)n*16, xn);
    stbf16x16(Pa + (size_t)n*16, pa);
    stbf16x16(Pc + (size_t)n*16, pc);
}

__global__ void node_mid(const float* __restrict__ agg,
                         const float* __restrict__ nw1, const float* __restrict__ nb1,
                         const float* __restrict__ nw2, const float* __restrict__ nb2,
                         const float* __restrict__ next_ew1,
                         unsigned short* __restrict__ Pa, unsigned short* __restrict__ Pc,
                         unsigned short* xnbf) {
    int n = blockIdx.x * blockDim.x + threadIdx.x;
    if (n >= NN) return;
    float o[16];
    ldbf16x16(xnbf + (size_t)n*16, o);
    #pragma unroll
    for (int j = 0; j < 16; ++j) o[j] += agg[(size_t)n*16 + j];
    float h[16];
    #pragma unroll
    for (int j = 0; j < 16; ++j) {
        float a = nb1[j];
        #pragma unroll
        for (int i = 0; i < 16; ++i) a = fmaf(o[i], nw1[i*16+j], a);
        h[j] = fmaxf(a, 0.f);
    }
    float xn[16];
    #pragma unroll
    for (int j = 0; j < 16; ++j) {
        float a = nb2[j];
        #pragma unroll
        for (int i = 0; i < 16; ++i) a = fmaf(h[i], nw2[i*16+j], a);
        xn[j] = fmaxf(a, 0.f);
    }
    float pa[16], pc[16];
    #pragma unroll
    for (int j = 0; j < 16; ++j) {
        float sa = 0.f, sc = 0.f;
        #pragma unroll
        for (int i = 0; i < 16; ++i) {
            sa = fmaf(xn[i], next_ew1[i*16+j], sa);
            sc = fmaf(xn[i], next_ew1[(32+i)*16+j], sc);
        }
        pa[j] = sa; pc[j] = sc;
    }
    stbf16x16(xnbf + (size_t)n*16, xn);
    stbf16x16(Pa + (size_t)n*16, pa);
    stbf16x16(Pc + (size_t)n*16, pc);
}

__global__ void node_last(const float* __restrict__ agg, const unsigned short* __restrict__ xnbf,
                          const float* __restrict__ nw1, const float* __restrict__ nb1,
                          const float* __restrict__ nw2, const float* __restrict__ nb2,
                          const float* __restrict__ hw1, const float* __restrict__ hb1,
                          const float* __restrict__ hw2, const float* __restrict__ hb2,
                          float* __restrict__ out_n) {
    int n = blockIdx.x * blockDim.x + threadIdx.x;
    if (n >= NN) return;
    float o[16];
    ldbf16x16(xnbf + (size_t)n*16, o);
    #pragma unroll
    for (int j = 0; j < 16; ++j) o[j] += agg[(size_t)n*16 + j];
    float h[16];
    #pragma unroll
    for (int j = 0; j < 16; ++j) {
        float a = nb1[j];
        #pragma unroll
        for (int i = 0; i < 16; ++i) a = fmaf(o[i], nw1[i*16+j], a);
        h[j] = fmaxf(a, 0.f);
    }
    float xn[16];
    #pragma unroll
    for (int j = 0; j < 16; ++j) {
        float a = nb2[j];
        #pragma unroll
        for (int i = 0; i < 16; ++i) a = fmaf(h[i], nw2[i*16+j], a);
        xn[j] = fmaxf(a, 0.f);
    }
    float g[16];
    #pragma unroll
    for (int j = 0; j < 16; ++j) {
        float a = hb1[j];
        #pragma unroll
        for (int i = 0; i < 16; ++i) a = fmaf(xn[i], hw1[i*16+j], a);
        g[j] = fmaxf(a, 0.f);
    }
    #pragma unroll
    for (int k = 0; k < 3; ++k) {
        float a = hb2[k];
        #pragma unroll
        for (int i = 0; i < 16; ++i) a = fmaf(g[i], hw2[i*3+k], a);
        out_n[(size_t)n*3 + k] = a;
    }
}

// ---------------- edge kernels (slot space, dst direct from srec) ----------------

__global__ void conv1_edge_s2(const unsigned long long* __restrict__ srec,
                              const unsigned int* __restrict__ ea_s,
                              const unsigned short* __restrict__ Pa, const unsigned short* __restrict__ Pc,
                              const float* __restrict__ ew1, const float* __restrict__ eb1,
                              const float* __restrict__ ew2, const float* __restrict__ eb2,
                              unsigned short* __restrict__ ebuf) {
    int j = blockIdx.x * blockDim.x + threadIdx.x;
    if (j >= NE) return;
    unsigned long long sr = ldnt_u64(&srec[j]);
    int s = (int)(sr & 0x1FFFFu);
    int t = (int)((sr >> 17) & 0x1FFFFu);
    uint2 wv = ldnt_u2(&ea_s[(size_t)2*j]);
    float e0 = bf2f(wv.x & 0xffffu), e1 = bf2f(wv.x >> 16), e2 = bf2f(wv.y & 0xffffu);
    float h[16], pc[16];
    ldbf16x16(Pa + (size_t)s*16, h);        // cached gather
    ldbf16x16(Pc + (size_t)t*16, pc);       // cached, dst-grouped
    #pragma unroll
    for (int jj = 0; jj < 16; ++jj) {
        float a = h[jj] + pc[jj] + eb1[jj]
                + e0*ew1[3*16+jj] + e1*ew1[4*16+jj] + e2*ew1[5*16+jj];
        h[jj] = fmaxf(a, 0.f);
    }
    float h2[16];
    #pragma unroll
    for (int jj = 0; jj < 16; ++jj) {
        float a = eb2[jj];
        #pragma unroll
        for (int i = 0; i < 16; ++i) a = fmaf(h[i], ew2[i*16+jj], a);
        h2[jj] = fmaxf(a, 0.f);
    }
    stbf16x16_nt(ebuf + (size_t)j*16, h2);
}

template <bool LAST>
__global__ void conv_edge2(const unsigned long long* __restrict__ srec,
                           unsigned short* ebuf,          // in-place per slot
                           const unsigned short* __restrict__ Pa, const unsigned short* __restrict__ Pc,
                           const float* __restrict__ ew1, const float* __restrict__ eb1,
                           const float* __restrict__ ew2, const float* __restrict__ eb2,
                           const float* __restrict__ hw1, const float* __restrict__ hb1,
                           const float* __restrict__ hw2, const float* __restrict__ hb2,
                           float* __restrict__ out_e) {
    int j = blockIdx.x * blockDim.x + threadIdx.x;
    if (j >= NE) return;
    unsigned long long sr = ldnt_u64(&srec[j]);
    int s = (int)(sr & 0x1FFFFu);
    int t = (int)((sr >> 17) & 0x1FFFFu);
    float ein[16], h[16], pc[16];
    ldbf16x16_nt(ebuf + (size_t)j*16, ein); // streaming
    ldbf16x16(Pa + (size_t)s*16, h);        // cached gather
    ldbf16x16(Pc + (size_t)t*16, pc);       // cached, dst-grouped
    #pragma unroll
    for (int jj = 0; jj < 16; ++jj) h[jj] = h[jj] + pc[jj] + eb1[jj];
    #pragma unroll
    for (int i = 0; i < 16; ++i) {
        #pragma unroll
        for (int jj = 0; jj < 16; ++jj) h[jj] = fmaf(ein[i], ew1[(16+i)*16+jj], h[jj]);
    }
    #pragma unroll
    for (int jj = 0; jj < 16; ++jj) h[jj] = fmaxf(h[jj], 0.f);
    float h2[16];
    #pragma unroll
    for (int jj = 0; jj < 16; ++jj) {
        float a = eb2[jj];
        #pragma unroll
        for (int i = 0; i < 16; ++i) a = fmaf(h[i], ew2[i*16+jj], a);
        h2[jj] = fmaxf(a, 0.f);
    }
    if (!LAST) {
        stbf16x16_nt(ebuf + (size_t)j*16, h2);
    } else {
        float g[16];
        #pragma unroll
        for (int jj = 0; jj < 16; ++jj) {
            float a = hb1[jj];
            #pragma unroll
            for (int i = 0; i < 16; ++i) a = fmaf(h2[i], hw1[i*16+jj], a);
            g[jj] = fmaxf(a, 0.f);
        }
        int e = (int)(sr >> 34);
        #pragma unroll
        for (int k = 0; k < 3; ++k) {
            float a = hb2[k];
            #pragma unroll
            for (int i = 0; i < 16; ++i) a = fmaf(g[i], hw2[i*3+k], a);
            out_e[(size_t)e*3 + k] = a;    // scatter: cached (L2 merges neighbors)
        }
    }
}

extern "C" void kernel_launch(void* const* d_in, const int* in_sizes, int n_in,
                              void* d_out, int out_size, void* d_ws, size_t ws_size,
                              hipStream_t stream) {
    const float* x  = (const float*)d_in[0];
    const float* ea = (const float*)d_in[1];
    const int*   ei = (const int*)d_in[2];
    const float *c1_ew1 = (const float*)d_in[3],  *c1_eb1 = (const float*)d_in[4];
    const float *c1_ew2 = (const float*)d_in[5],  *c1_eb2 = (const float*)d_in[6];
    const float *c1_nw1 = (const float*)d_in[7],  *c1_nb1 = (const float*)d_in[8];
    const float *c1_nw2 = (const float*)d_in[9],  *c1_nb2 = (const float*)d_in[10];
    const float *c2_ew1 = (const float*)d_in[11], *c2_eb1 = (const float*)d_in[12];
    const float *c2_ew2 = (const float*)d_in[13], *c2_eb2 = (const float*)d_in[14];
    const float *c2_nw1 = (const float*)d_in[15], *c2_nb1 = (const float*)d_in[16];
    const float *c2_nw2 = (const float*)d_in[17], *c2_nb2 = (const float*)d_in[18];
    const float *c3_ew1 = (const float*)d_in[19], *c3_eb1 = (const float*)d_in[20];
    const float *c3_ew2 = (const float*)d_in[21], *c3_eb2 = (const float*)d_in[22];
    const float *c3_nw1 = (const float*)d_in[23], *c3_nb1 = (const float*)d_in[24];
    const float *c3_nw2 = (const float*)d_in[25], *c3_nb2 = (const float*)d_in[26];
    const float *node_w1 = (const float*)d_in[27], *node_b1 = (const float*)d_in[28];
    const float *node_w2 = (const float*)d_in[29], *node_b2 = (const float*)d_in[30];
    const float *edge_w1 = (const float*)d_in[31], *edge_b1 = (const float*)d_in[32];
    const float *edge_w2 = (const float*)d_in[33], *edge_b2 = (const float*)d_in[34];

    // ---- ws carve-up (137.6 MB) ----
    char* w = (char*)d_ws;
    unsigned short* ebuf = (unsigned short*)w;               // NE*32; build scratch aliases inside:
    uint4* brec16 = (uint4*)w;                               //   NE*16 = 51.2 MB
    int* hist   = (int*)(w + (size_t)NE*16);                 //   NBKT*NBLK1*4 = 3.2 MB
    int* binsum = hist + NBKT * NBLK1;                       //   782*4
    int* binbase = binsum + NBKT;                            //   783*4
    w += (size_t)NE * 32;
    unsigned long long* srec = (unsigned long long*)w;  w += (size_t)NE * 8;   // 25.6 MB
    unsigned short* Pa   = (unsigned short*)w;          w += (size_t)NN * 32;
    unsigned short* Pc   = (unsigned short*)w;          w += (size_t)NN * 32;
    unsigned short* xnbf = (unsigned short*)w;          w += (size_t)NN * 32;

    // ---- d_out overlays ----
    float* out_n = (float*)d_out;                      // N*3 floats (1.2 MB)
    float* out_e = out_n + (size_t)NN * 3;             // E*3 floats (38.4 MB)
    int* start = (int*)out_n;                          // (NN+1)*4, dead before node_last
    unsigned int* ea_s = (unsigned int*)out_e;                 // NE*8 = 25.6 MB
    float* agg = (float*)((char*)out_e + (size_t)NE * 8);      // N*16 f32 = 6.4 MB

    const int B = 256;
    const int gn = (NN + B - 1) / B;                 // 391
    const int ge = (NE + B - 1) / B;                 // 12500
    const int gq = (NN * 4 + B - 1) / B;             // 1563

    // ---- build (no global atomics) ----
    khist1<<<NBLK1, B, 0, stream>>>(ei, hist);
    kscan_a<<<NBKT, NBLK1, 0, stream>>>(hist, binsum);
    kscan_b<<<1, 1024, 0, stream>>>(binsum, binbase, start);
    kscatter1<<<NBLK1, B, 0, stream>>>(ei, ea, hist, binbase, brec16);
    kbucket<<<NBKT, B, 0, stream>>>(brec16, binbase, srec, ea_s, start);

    // ---- conv1 ----
    prep1<<<gn, B, 0, stream>>>(x, c1_ew1, Pa, Pc);
    kagg3_s<<<gq, B, 0, stream>>>(start, srec, ea_s, x, agg);
    conv1_edge_s2<<<ge, B, 0, stream>>>(srec, ea_s, Pa, Pc,
                                        c1_ew1, c1_eb1, c1_ew2, c1_eb2, ebuf);
    conv1_node<<<gn, B, 0, stream>>>(agg, x, c1_nw1, c1_nb1, c1_nw2, c1_nb2,
                                     c2_ew1, Pa, Pc, xnbf);
    // ---- conv2 ----
    kagg16_s<<<gq, B, 0, stream>>>(start, srec, ebuf, xnbf, agg);
    conv_edge2<false><<<ge, B, 0, stream>>>(srec, ebuf, Pa, Pc,
                                            c2_ew1, c2_eb1, c2_ew2, c2_eb2,
                                            nullptr, nullptr, nullptr, nullptr, nullptr);
    node_mid<<<gn, B, 0, stream>>>(agg, c2_nw1, c2_nb1, c2_nw2, c2_nb2,
                                   c3_ew1, Pa, Pc, xnbf);
    // ---- conv3 ----
    kagg16_s<<<gq, B, 0, stream>>>(start, srec, ebuf, xnbf, agg);
    node_last<<<gn, B, 0, stream>>>(agg, xnbf, c3_nw1, c3_nb1, c3_nw2, c3_nb2,
                                    node_w1, node_b1, node_w2, node_b2, out_n);
    conv_edge2<true><<<ge, B, 0, stream>>>(srec, ebuf, Pa, Pc,
                                           c3_ew1, c3_eb1, c3_ew2, c3_eb2,
                                           edge_w1, edge_b1, edge_w2, edge_b2, out_e);
}